// Round 12
// baseline (104.650 us; speedup 1.0000x reference)
//
#include <hip/hip_runtime.h>

// CondInst dynamic mask head, split into 2 kernels (R12):
//  K1 dmh_mlp:      per-instance MLP (10->8->8->1, x2 heads) -> f16 mask at
//                   200-res into d_ws. One 4-px pass per thread (no loop, no
//                   weight reloads, no halo). Weights packed in LDS.
//  K2 dmh_upsample: aligned_bilinear x2 + fast sigmoid, streaming from the
//                   L3-resident f16 buffer, nt f32 stores.
// Fallback: if ws_size < needed, launch the proven R11 fused kernel.

#define BLOCK 256
#define Hh 200
#define Ww 200
#define NP 169
#define TH 25      // fused fallback: output rows per tile
#define MAXR 14
#define OW 400
#define OH 400

typedef float f32x4 __attribute__((ext_vector_type(4)));
typedef float f32x2 __attribute__((ext_vector_type(2)));
typedef _Float16 f16x4 __attribute__((ext_vector_type(4)));

__device__ __forceinline__ f32x2 splat2(float v) { f32x2 r; r.x = v; r.y = v; return r; }
__device__ __forceinline__ f32x2 pkfma(f32x2 a, f32x2 b, f32x2 c) {
    return __builtin_elementwise_fma(a, b, c);
}

// packed per-head layout (192 floats, 16B-aligned rows):
//   w0 rows (8 x 10) stride 12 -> [0,96) ; w1 (8 x 8) -> [96,160)
//   w2 (8) -> [160,168) ; b0 [168,176) ; b1 [176,184) ; b2 [184]
__device__ __forceinline__ int park_dst(int k) {
    if (k < 80)  return (k / 10) * 12 + (k % 10);
    if (k < 144) return 96 + (k - 80);
    if (k < 152) return 160 + (k - 144);
    if (k < 160) return 168 + (k - 152);
    if (k < 168) return 176 + (k - 160);
    return 184;
}

// 3-layer MLP on 4 px (xa = px{0,1}, xb = px{2,3}); weights at P (LDS).
__device__ __forceinline__ void mlp4(const float* __restrict__ P,
    const f32x2 (&xa)[10], const f32x2 (&xb)[10], f32x2& oa_, f32x2& ob_)
{
    const f32x2 zero = splat2(0.0f);

    f32x2 h1a[8], h1b[8];
    #pragma unroll
    for (int o = 0; o < 8; o++) {
        const f32x4 wa = *(const f32x4*)(P + o * 12);
        const f32x4 wb = *(const f32x4*)(P + o * 12 + 4);
        const float w8 = P[o * 12 + 8];
        const float w9 = P[o * 12 + 9];
        f32x2 aa = splat2(P[168 + o]);
        f32x2 ab = aa;
        aa = pkfma(splat2(wa.x), xa[0], aa); ab = pkfma(splat2(wa.x), xb[0], ab);
        aa = pkfma(splat2(wa.y), xa[1], aa); ab = pkfma(splat2(wa.y), xb[1], ab);
        aa = pkfma(splat2(wa.z), xa[2], aa); ab = pkfma(splat2(wa.z), xb[2], ab);
        aa = pkfma(splat2(wa.w), xa[3], aa); ab = pkfma(splat2(wa.w), xb[3], ab);
        aa = pkfma(splat2(wb.x), xa[4], aa); ab = pkfma(splat2(wb.x), xb[4], ab);
        aa = pkfma(splat2(wb.y), xa[5], aa); ab = pkfma(splat2(wb.y), xb[5], ab);
        aa = pkfma(splat2(wb.z), xa[6], aa); ab = pkfma(splat2(wb.z), xb[6], ab);
        aa = pkfma(splat2(wb.w), xa[7], aa); ab = pkfma(splat2(wb.w), xb[7], ab);
        aa = pkfma(splat2(w8),   xa[8], aa); ab = pkfma(splat2(w8),   xb[8], ab);
        aa = pkfma(splat2(w9),   xa[9], aa); ab = pkfma(splat2(w9),   xb[9], ab);
        h1a[o] = __builtin_elementwise_max(aa, zero);
        h1b[o] = __builtin_elementwise_max(ab, zero);
    }

    f32x2 h2a[8], h2b[8];
    #pragma unroll
    for (int o = 0; o < 8; o++) {
        const f32x4 wa = *(const f32x4*)(P + 96 + o * 8);
        const f32x4 wb = *(const f32x4*)(P + 96 + o * 8 + 4);
        f32x2 aa = splat2(P[176 + o]);
        f32x2 ab = aa;
        aa = pkfma(splat2(wa.x), h1a[0], aa); ab = pkfma(splat2(wa.x), h1b[0], ab);
        aa = pkfma(splat2(wa.y), h1a[1], aa); ab = pkfma(splat2(wa.y), h1b[1], ab);
        aa = pkfma(splat2(wa.z), h1a[2], aa); ab = pkfma(splat2(wa.z), h1b[2], ab);
        aa = pkfma(splat2(wa.w), h1a[3], aa); ab = pkfma(splat2(wa.w), h1b[3], ab);
        aa = pkfma(splat2(wb.x), h1a[4], aa); ab = pkfma(splat2(wb.x), h1b[4], ab);
        aa = pkfma(splat2(wb.y), h1a[5], aa); ab = pkfma(splat2(wb.y), h1b[5], ab);
        aa = pkfma(splat2(wb.z), h1a[6], aa); ab = pkfma(splat2(wb.z), h1b[6], ab);
        aa = pkfma(splat2(wb.w), h1a[7], aa); ab = pkfma(splat2(wb.w), h1b[7], ab);
        h2a[o] = __builtin_elementwise_max(aa, zero);
        h2b[o] = __builtin_elementwise_max(ab, zero);
    }

    const f32x4 wa = *(const f32x4*)(P + 160);
    const f32x4 wb = *(const f32x4*)(P + 164);
    f32x2 aa = splat2(P[184]);
    f32x2 ab = aa;
    aa = pkfma(splat2(wa.x), h2a[0], aa); ab = pkfma(splat2(wa.x), h2b[0], ab);
    aa = pkfma(splat2(wa.y), h2a[1], aa); ab = pkfma(splat2(wa.y), h2b[1], ab);
    aa = pkfma(splat2(wa.z), h2a[2], aa); ab = pkfma(splat2(wa.z), h2b[2], ab);
    aa = pkfma(splat2(wa.w), h2a[3], aa); ab = pkfma(splat2(wa.w), h2b[3], ab);
    aa = pkfma(splat2(wb.x), h2a[4], aa); ab = pkfma(splat2(wb.x), h2b[4], ab);
    aa = pkfma(splat2(wb.y), h2a[5], aa); ab = pkfma(splat2(wb.y), h2b[5], ab);
    aa = pkfma(splat2(wb.z), h2a[6], aa); ab = pkfma(splat2(wb.z), h2b[6], ab);
    aa = pkfma(splat2(wb.w), h2a[7], aa); ab = pkfma(splat2(wb.w), h2b[7], ab);
    oa_ = aa; ob_ = ab;
}

// ---------------- K1: MLP -> f16 mask at 200-res ----------------
__global__ __launch_bounds__(BLOCK, 4) void dmh_mlp(
    const float* __restrict__ mask_feats,
    const float* __restrict__ mparams,
    const float* __restrict__ bparams,
    const float* __restrict__ ilocs,
    const int*   __restrict__ im_inds,
    const int*   __restrict__ fpn_levels,
    const int*   __restrict__ stride_p,
    _Float16* __restrict__ mbuf)          // [n_inst][2][200][200]
{
    __shared__ __align__(16) float s_par[2 * 192];
    const int tid   = threadIdx.x;
    const int strip = blockIdx.x;          // 0..39, 1000 px each
    const int inst  = blockIdx.y;

    for (int j = tid; j < 2 * NP; j += BLOCK) {
        const int head = (j < NP) ? 0 : 1;
        const int k = j - head * NP;
        const float v = head ? bparams[inst * NP + k] : mparams[inst * NP + k];
        s_par[head * 192 + park_dst(k)] = v;
    }

    const int   s    = stride_p[0];
    const int   half = s >> 1;
    const int   im   = im_inds[inst];
    const int   lvl  = fpn_levels[inst];
    const float inv_soi = 1.0f / (float)(64 << lvl);
    const float ixl = ilocs[inst * 2 + 0];
    const float iyl = ilocs[inst * 2 + 1];

    __syncthreads();
    if (tid >= 250) return;                // 250 threads x 4 px = 1000 px

    const int px = strip * 1000 + tid * 4;
    const int r  = px / 200;
    const int c  = px - r * 200;           // multiple of 4
    const float* fbase = mask_feats + (size_t)im * 8 * Hh * Ww;

    f32x2 xa[10], xb[10];
    {
        const float ry   = (iyl - (float)(r * s + half)) * inv_soi;
        const float step = -(float)s * inv_soi;
        const float cx0  = (ixl - (float)(c * s + half)) * inv_soi;
        xa[0].x = cx0;            xa[0].y = cx0 + step;
        xb[0].x = cx0 + 2*step;   xb[0].y = cx0 + 3*step;
        xa[1] = splat2(ry);       xb[1] = xa[1];
        const float* fp = fbase + r * Ww + c;
        #pragma unroll
        for (int ch = 0; ch < 8; ch++) {
            const f32x4 f = *(const f32x4*)(fp + ch * (Hh * Ww));
            xa[2 + ch].x = f.x; xa[2 + ch].y = f.y;
            xb[2 + ch].x = f.z; xb[2 + ch].y = f.w;
        }
    }

    #pragma unroll 1
    for (int head = 0; head < 2; head++) {
        f32x2 oa, ob;
        mlp4(s_par + head * 192, xa, xb, oa, ob);
        f16x4 res;
        res.x = (_Float16)oa.x; res.y = (_Float16)oa.y;
        res.z = (_Float16)ob.x; res.w = (_Float16)ob.y;
        *(f16x4*)(mbuf + ((size_t)(inst * 2 + head) * 40000 + r * 200 + c)) = res;
    }
}

// ---------------- K2: aligned_bilinear x2 + sigmoid (streaming) ----------------
__global__ __launch_bounds__(BLOCK, 4) void dmh_upsample(
    const _Float16* __restrict__ mbuf,
    float* __restrict__ out, int n_inst)
{
    const int t = blockIdx.x * BLOCK + threadIdx.x;   // task = 8 out px, both heads
    if (t >= n_inst * 20000) return;                  // 400 rows x 50 groups
    const int inst = t / 20000;
    const int rem  = t - inst * 20000;
    const int row  = rem / 50;
    const int u    = rem - row * 50;

    const int ip = (row > 0) ? (row - 1) : 0;
    const int y0 = ip >> 1;
    const int y1 = (y0 + 1 <= Hh - 1) ? (y0 + 1) : (Hh - 1);
    const float wy = (ip & 1) ? 0.5f : 0.0f;
    const float C = -1.44269504f;   // -log2(e), folded into y-interp

    float* out0 = out + (size_t)inst * (OH * OW) + row * OW + 8 * u;
    float* out1 = out0 + (size_t)n_inst * (OH * OW);

    #pragma unroll
    for (int head = 0; head < 2; head++) {
        const _Float16* m0 = mbuf + ((size_t)(inst * 2 + head) * 40000 + y0 * 200);
        const _Float16* m1 = mbuf + ((size_t)(inst * 2 + head) * 40000 + y1 * 200);
        const f16x4 A0 = *(const f16x4*)(m0 + 4 * u);
        const f16x4 A1 = *(const f16x4*)(m1 + 4 * u);
        float p0 = 0.0f, p1 = 0.0f;
        if (u > 0) { p0 = (float)m0[4 * u - 1]; p1 = (float)m1[4 * u - 1]; }

        float Bv[4];
        #pragma unroll
        for (int m = 0; m < 4; m++) {
            const float a0 = (float)A0[m], a1 = (float)A1[m];
            Bv[m] = (a0 + (a1 - a0) * wy) * C;
        }
        const float PB = (p0 + (p1 - p0) * wy) * C;

        float e[8];
        e[0] = (u > 0) ? 0.5f * (PB + Bv[0]) : Bv[0];
        e[1] = Bv[0];
        e[2] = 0.5f * (Bv[0] + Bv[1]);
        e[3] = Bv[1];
        e[4] = 0.5f * (Bv[1] + Bv[2]);
        e[5] = Bv[2];
        e[6] = 0.5f * (Bv[2] + Bv[3]);
        e[7] = Bv[3];

        f32x4 lo, hi;
        #pragma unroll
        for (int k = 0; k < 4; k++) {
            lo[k] = __builtin_amdgcn_rcpf(1.0f + __builtin_amdgcn_exp2f(e[k]));
            hi[k] = __builtin_amdgcn_rcpf(1.0f + __builtin_amdgcn_exp2f(e[4 + k]));
        }
        float* dst = head ? out1 : out0;
        __builtin_nontemporal_store(lo, (f32x4*)dst);
        __builtin_nontemporal_store(hi, (f32x4*)(dst + 4));
    }
}

// ---------------- Fallback: proven R11 fused kernel ----------------
__global__ __launch_bounds__(BLOCK, 4) void dmh_fused(
    const float* __restrict__ mask_feats,
    const float* __restrict__ mparams,
    const float* __restrict__ bparams,
    const float* __restrict__ ilocs,
    const int*   __restrict__ im_inds,
    const int*   __restrict__ fpn_levels,
    const int*   __restrict__ stride_p,
    float* __restrict__ out,
    int n_inst)
{
    __shared__ __align__(16) float s_par[2 * 192];
    __shared__ __align__(16) _Float16 s_m[2][MAXR][Ww];

    const int tid  = threadIdx.x;
    const int tile = blockIdx.x;
    const int inst = blockIdx.y;

    for (int j = tid; j < 2 * NP; j += BLOCK) {
        const int head = (j < NP) ? 0 : 1;
        const int k = j - head * NP;
        const float v = head ? bparams[inst * NP + k] : mparams[inst * NP + k];
        s_par[head * 192 + park_dst(k)] = v;
    }

    const int   s    = stride_p[0];
    const int   half = s >> 1;
    const int   im   = im_inds[inst];
    const int   lvl  = fpn_levels[inst];
    const float inv_soi = 1.0f / (float)(64 << lvl);
    const float ixl = ilocs[inst * 2 + 0];
    const float iyl = ilocs[inst * 2 + 1];

    const int i0 = tile * TH;
    const int r_begin = ((i0 > 0) ? (i0 - 1) : 0) >> 1;
    int r_end = ((i0 + TH - 2) >> 1) + 1;
    if (r_end > Hh - 1) r_end = Hh - 1;
    const int nrows = r_end - r_begin + 1;

    __syncthreads();

    const int npx = nrows * Ww;
    const float* fbase = mask_feats + (size_t)im * 8 * Hh * Ww;

    for (int g = tid * 4; g < npx; g += BLOCK * 4) {
        asm volatile("" ::: "memory");
        const int lr = g / Ww;
        const int c  = g - lr * Ww;
        const int r  = r_begin + lr;

        f32x2 xa[10], xb[10];
        {
            const float ry   = (iyl - (float)(r * s + half)) * inv_soi;
            const float step = -(float)s * inv_soi;
            const float cx0  = (ixl - (float)(c * s + half)) * inv_soi;
            xa[0].x = cx0;            xa[0].y = cx0 + step;
            xb[0].x = cx0 + 2*step;   xb[0].y = cx0 + 3*step;
            xa[1] = splat2(ry);       xb[1] = xa[1];
            const float* fp = fbase + r * Ww + c;
            #pragma unroll
            for (int ch = 0; ch < 8; ch++) {
                const f32x4 f = *(const f32x4*)(fp + ch * (Hh * Ww));
                xa[2 + ch].x = f.x; xa[2 + ch].y = f.y;
                xb[2 + ch].x = f.z; xb[2 + ch].y = f.w;
            }
        }

        #pragma unroll 1
        for (int head = 0; head < 2; head++) {
            f32x2 oa, ob;
            mlp4(s_par + head * 192, xa, xb, oa, ob);
            f16x4 res;
            res.x = (_Float16)oa.x; res.y = (_Float16)oa.y;
            res.z = (_Float16)ob.x; res.w = (_Float16)ob.y;
            *(f16x4*)(&s_m[head][lr][c]) = res;
        }
    }

    __syncthreads();

    float* out0 = out + (size_t)inst * (OH * OW) + (size_t)i0 * OW;
    float* out1 = out0 + (size_t)n_inst * (OH * OW);

    const float C = -1.44269504f;
    const int NU = OW / 8;
    const int ntaskb = TH * NU;
    for (int t = tid; t < ntaskb; t += BLOCK) {
        const int row = t / NU;
        const int u   = t - row * NU;
        const int i   = i0 + row;
        const int ip  = (i > 0) ? (i - 1) : 0;
        const int y0  = ip >> 1;
        const float wy = (ip & 1) ? 0.5f : 0.0f;
        const int lr0 = y0 - r_begin;
        const int r1c = (y0 + 1 <= Hh - 1) ? (y0 + 1) : (Hh - 1);
        const int lr1 = r1c - r_begin;

        #pragma unroll
        for (int head = 0; head < 2; head++) {
            const f16x4 A0h = *(const f16x4*)(&s_m[head][lr0][4 * u]);
            const f16x4 A1h = *(const f16x4*)(&s_m[head][lr1][4 * u]);
            float p0 = 0.0f, p1 = 0.0f;
            if (u > 0) {
                p0 = (float)s_m[head][lr0][4 * u - 1];
                p1 = (float)s_m[head][lr1][4 * u - 1];
            }
            float Bv[4];
            #pragma unroll
            for (int m = 0; m < 4; m++) {
                const float a0 = (float)A0h[m], a1 = (float)A1h[m];
                Bv[m] = (a0 + (a1 - a0) * wy) * C;
            }
            const float PB = (p0 + (p1 - p0) * wy) * C;

            float e[8];
            e[0] = (u > 0) ? 0.5f * (PB + Bv[0]) : Bv[0];
            e[1] = Bv[0];
            e[2] = 0.5f * (Bv[0] + Bv[1]);
            e[3] = Bv[1];
            e[4] = 0.5f * (Bv[1] + Bv[2]);
            e[5] = Bv[2];
            e[6] = 0.5f * (Bv[2] + Bv[3]);
            e[7] = Bv[3];

            f32x4 lo, hi;
            #pragma unroll
            for (int k = 0; k < 4; k++) {
                lo[k] = __builtin_amdgcn_rcpf(1.0f + __builtin_amdgcn_exp2f(e[k]));
                hi[k] = __builtin_amdgcn_rcpf(1.0f + __builtin_amdgcn_exp2f(e[4 + k]));
            }

            float* dst = (head ? out1 : out0) + row * OW + 8 * u;
            __builtin_nontemporal_store(lo, (f32x4*)dst);
            __builtin_nontemporal_store(hi, (f32x4*)(dst + 4));
        }
    }
}

extern "C" void kernel_launch(void* const* d_in, const int* in_sizes, int n_in,
                              void* d_out, int out_size, void* d_ws, size_t ws_size,
                              hipStream_t stream) {
    const float* mask_feats = (const float*)d_in[0];
    const float* mparams    = (const float*)d_in[1];
    const float* bparams    = (const float*)d_in[2];
    const float* ilocs      = (const float*)d_in[3];
    const int*   im_inds    = (const int*)d_in[4];
    const int*   fpn_levels = (const int*)d_in[5];
    const int*   stride_p   = (const int*)d_in[6];
    float* out = (float*)d_out;

    const int n_inst = in_sizes[1] / NP;                     // 128
    const size_t need = (size_t)n_inst * 2 * 40000 * sizeof(_Float16);  // 20.48 MB

    if (ws_size >= need) {
        _Float16* mbuf = (_Float16*)d_ws;
        hipLaunchKernelGGL(dmh_mlp, dim3(40, n_inst), dim3(BLOCK), 0, stream,
                           mask_feats, mparams, bparams, ilocs,
                           im_inds, fpn_levels, stride_p, mbuf);
        const int ntask = n_inst * 20000;
        hipLaunchKernelGGL(dmh_upsample, dim3((ntask + BLOCK - 1) / BLOCK),
                           dim3(BLOCK), 0, stream, mbuf, out, n_inst);
    } else {
        dim3 grid(OH / TH, n_inst);
        hipLaunchKernelGGL(dmh_fused, grid, dim3(BLOCK), 0, stream,
                           mask_feats, mparams, bparams, ilocs,
                           im_inds, fpn_levels, stride_p, out, n_inst);
    }
}

// Round 13
// 93.720 us; speedup vs baseline: 1.1166x; 1.1166x over previous
//
#include <hip/hip_runtime.h>

// CondInst dynamic mask head, fused (R13 = R11 + duplicated-weight LDS layout).
// mask_feats (2,8,200,200) f32, params (128,169) f32 x2, locs (128,2) f32,
// im_inds/fpn_levels int32, stride scalar int (=8).
// Output: 2 x (128,1,400,400) f32 concat flat.
//
// R13 change: weights stored in LDS as {w,w} 64-bit pairs so v_pk_fma_f32
// consumes them directly (no splat2 -> no potential per-FMA v_mov dup).
// Loaded as b128 (2 pairs/read), halves extracted as free subregisters.

#define BLOCK 256
#define Hh 200
#define Ww 200
#define NP 169
#define TH 25      // output rows per tile
#define MAXR 14    // max head rows needed per tile (factor=2)
#define OW 400
#define OH 400
#define PSTR 384   // per-head packed-param stride (floats)

typedef float f32x4 __attribute__((ext_vector_type(4)));
typedef float f32x2 __attribute__((ext_vector_type(2)));
typedef _Float16 f16x4 __attribute__((ext_vector_type(4)));

#define LO2(v) __builtin_shufflevector(v, v, 0, 1)
#define HI2(v) __builtin_shufflevector(v, v, 2, 3)

__device__ __forceinline__ f32x2 splat2(float v) { f32x2 r; r.x = v; r.y = v; return r; }
__device__ __forceinline__ f32x2 pkfma(f32x2 a, f32x2 b, f32x2 c) {
    return __builtin_elementwise_fma(a, b, c);
}

// duplicated per-head layout (PSTR floats, all 16B-aligned rows):
//   L1 row o at o*24:  {w,w} j=0..9 at 2j, bias pair at 20, pad 22
//   L2 row o at 192+o*20: {w,w} j=0..7 at 2j, bias pair at 16, pad 18
//   L3 at 352: {w,w} j=0..7, bias pair at 16, pad 18
__device__ __forceinline__ int park_dst(int k) {
    if (k < 80)  { const int o = k / 10; return o * 24 + 2 * (k - 10 * o); }
    if (k < 144) { const int kk = k - 80; return 192 + (kk >> 3) * 20 + 2 * (kk & 7); }
    if (k < 152) return 352 + 2 * (k - 144);
    if (k < 160) return (k - 152) * 24 + 20;
    if (k < 168) return 192 + (k - 160) * 20 + 16;
    return 352 + 16;
}

// 3-layer MLP on 4 px (xa = px{0,1}, xb = px{2,3}); duplicated weights at P.
__device__ __forceinline__ void mlp4(const float* __restrict__ P,
    const f32x2 (&xa)[10], const f32x2 (&xb)[10], f32x2& oa_, f32x2& ob_)
{
    const f32x2 zero = splat2(0.0f);

    f32x2 h1a[8], h1b[8];
    #pragma unroll
    for (int o = 0; o < 8; o++) {
        const float* R = P + o * 24;
        const f32x4 q0 = *(const f32x4*)(R + 0);    // w0w0 w1w1
        const f32x4 q1 = *(const f32x4*)(R + 4);    // w2w2 w3w3
        const f32x4 q2 = *(const f32x4*)(R + 8);    // w4w4 w5w5
        const f32x4 q3 = *(const f32x4*)(R + 12);   // w6w6 w7w7
        const f32x4 q4 = *(const f32x4*)(R + 16);   // w8w8 w9w9
        const f32x2 bb = *(const f32x2*)(R + 20);   // b b
        f32x2 aa = bb, ab = bb;
        aa = pkfma(LO2(q0), xa[0], aa); ab = pkfma(LO2(q0), xb[0], ab);
        aa = pkfma(HI2(q0), xa[1], aa); ab = pkfma(HI2(q0), xb[1], ab);
        aa = pkfma(LO2(q1), xa[2], aa); ab = pkfma(LO2(q1), xb[2], ab);
        aa = pkfma(HI2(q1), xa[3], aa); ab = pkfma(HI2(q1), xb[3], ab);
        aa = pkfma(LO2(q2), xa[4], aa); ab = pkfma(LO2(q2), xb[4], ab);
        aa = pkfma(HI2(q2), xa[5], aa); ab = pkfma(HI2(q2), xb[5], ab);
        aa = pkfma(LO2(q3), xa[6], aa); ab = pkfma(LO2(q3), xb[6], ab);
        aa = pkfma(HI2(q3), xa[7], aa); ab = pkfma(HI2(q3), xb[7], ab);
        aa = pkfma(LO2(q4), xa[8], aa); ab = pkfma(LO2(q4), xb[8], ab);
        aa = pkfma(HI2(q4), xa[9], aa); ab = pkfma(HI2(q4), xb[9], ab);
        h1a[o] = __builtin_elementwise_max(aa, zero);
        h1b[o] = __builtin_elementwise_max(ab, zero);
    }

    f32x2 h2a[8], h2b[8];
    #pragma unroll
    for (int o = 0; o < 8; o++) {
        const float* R = P + 192 + o * 20;
        const f32x4 q0 = *(const f32x4*)(R + 0);
        const f32x4 q1 = *(const f32x4*)(R + 4);
        const f32x4 q2 = *(const f32x4*)(R + 8);
        const f32x4 q3 = *(const f32x4*)(R + 12);
        const f32x2 bb = *(const f32x2*)(R + 16);
        f32x2 aa = bb, ab = bb;
        aa = pkfma(LO2(q0), h1a[0], aa); ab = pkfma(LO2(q0), h1b[0], ab);
        aa = pkfma(HI2(q0), h1a[1], aa); ab = pkfma(HI2(q0), h1b[1], ab);
        aa = pkfma(LO2(q1), h1a[2], aa); ab = pkfma(LO2(q1), h1b[2], ab);
        aa = pkfma(HI2(q1), h1a[3], aa); ab = pkfma(HI2(q1), h1b[3], ab);
        aa = pkfma(LO2(q2), h1a[4], aa); ab = pkfma(LO2(q2), h1b[4], ab);
        aa = pkfma(HI2(q2), h1a[5], aa); ab = pkfma(HI2(q2), h1b[5], ab);
        aa = pkfma(LO2(q3), h1a[6], aa); ab = pkfma(LO2(q3), h1b[6], ab);
        aa = pkfma(HI2(q3), h1a[7], aa); ab = pkfma(HI2(q3), h1b[7], ab);
        h2a[o] = __builtin_elementwise_max(aa, zero);
        h2b[o] = __builtin_elementwise_max(ab, zero);
    }

    {
        const float* R = P + 352;
        const f32x4 q0 = *(const f32x4*)(R + 0);
        const f32x4 q1 = *(const f32x4*)(R + 4);
        const f32x4 q2 = *(const f32x4*)(R + 8);
        const f32x4 q3 = *(const f32x4*)(R + 12);
        const f32x2 bb = *(const f32x2*)(R + 16);
        f32x2 aa = bb, ab = bb;
        aa = pkfma(LO2(q0), h2a[0], aa); ab = pkfma(LO2(q0), h2b[0], ab);
        aa = pkfma(HI2(q0), h2a[1], aa); ab = pkfma(HI2(q0), h2b[1], ab);
        aa = pkfma(LO2(q1), h2a[2], aa); ab = pkfma(LO2(q1), h2b[2], ab);
        aa = pkfma(HI2(q1), h2a[3], aa); ab = pkfma(HI2(q1), h2b[3], ab);
        aa = pkfma(LO2(q2), h2a[4], aa); ab = pkfma(LO2(q2), h2b[4], ab);
        aa = pkfma(HI2(q2), h2a[5], aa); ab = pkfma(HI2(q2), h2b[5], ab);
        aa = pkfma(LO2(q3), h2a[6], aa); ab = pkfma(LO2(q3), h2b[6], ab);
        aa = pkfma(HI2(q3), h2a[7], aa); ab = pkfma(HI2(q3), h2b[7], ab);
        oa_ = aa; ob_ = ab;
    }
}

__global__ __launch_bounds__(BLOCK, 4) void dmh_fused(
    const float* __restrict__ mask_feats,
    const float* __restrict__ mparams,
    const float* __restrict__ bparams,
    const float* __restrict__ ilocs,
    const int*   __restrict__ im_inds,
    const int*   __restrict__ fpn_levels,
    const int*   __restrict__ stride_p,
    float* __restrict__ out,
    int n_inst)
{
    __shared__ __align__(16) float s_par[2 * PSTR];        // 3 KB
    __shared__ __align__(16) _Float16 s_m[2][MAXR][Ww];    // 11.2 KB

    const int tid  = threadIdx.x;
    const int tile = blockIdx.x;   // 0..15
    const int inst = blockIdx.y;

    for (int j = tid; j < 2 * NP; j += BLOCK) {
        const int head = (j < NP) ? 0 : 1;
        const int k = j - head * NP;
        const float v = head ? bparams[inst * NP + k] : mparams[inst * NP + k];
        const int dst = head * PSTR + park_dst(k);
        s_par[dst] = v;
        s_par[dst + 1] = v;
    }

    const int   s    = stride_p[0];       // 8
    const int   half = s >> 1;
    const int   im   = im_inds[inst];
    const int   lvl  = fpn_levels[inst];
    const float inv_soi = 1.0f / (float)(64 << lvl);  // SOI = 64*2^lvl exactly
    const float ixl = ilocs[inst * 2 + 0];
    const float iyl = ilocs[inst * 2 + 1];

    const int i0 = tile * TH;
    const int r_begin = ((i0 > 0) ? (i0 - 1) : 0) >> 1;
    int r_end = ((i0 + TH - 2) >> 1) + 1;
    if (r_end > Hh - 1) r_end = Hh - 1;
    const int nrows = r_end - r_begin + 1;   // 13 or 14

    __syncthreads();

    // ---------- Phase A: head MLP at 200-res into LDS (pk-f32, 4 px/chunk) ----------
    const int npx = nrows * Ww;                 // multiple of 4
    const float* fbase = mask_feats + (size_t)im * 8 * Hh * Ww;

    for (int g = tid * 4; g < npx; g += BLOCK * 4) {
        // prevent hoisting of LDS weight loads across iterations (VGPR blowup)
        asm volatile("" ::: "memory");

        const int lr = g / Ww;
        const int c  = g - lr * Ww;             // multiple of 4
        const int r  = r_begin + lr;

        // xa = px {0,1}, xb = px {2,3} for the 10 input channels
        f32x2 xa[10], xb[10];
        {
            const float ry   = (iyl - (float)(r * s + half)) * inv_soi;
            const float step = -(float)s * inv_soi;
            const float cx0  = (ixl - (float)(c * s + half)) * inv_soi;
            xa[0].x = cx0;            xa[0].y = cx0 + step;
            xb[0].x = cx0 + 2*step;   xb[0].y = cx0 + 3*step;
            xa[1] = splat2(ry);       xb[1] = xa[1];
            const float* fp = fbase + r * Ww + c;
            #pragma unroll
            for (int ch = 0; ch < 8; ch++) {
                const f32x4 f = *(const f32x4*)(fp + ch * (Hh * Ww));
                xa[2 + ch].x = f.x; xa[2 + ch].y = f.y;
                xb[2 + ch].x = f.z; xb[2 + ch].y = f.w;
            }
        }

        #pragma unroll 1
        for (int head = 0; head < 2; head++) {
            f32x2 oa, ob;
            mlp4(s_par + head * PSTR, xa, xb, oa, ob);
            f16x4 res;
            res.x = (_Float16)oa.x; res.y = (_Float16)oa.y;
            res.z = (_Float16)ob.x; res.w = (_Float16)ob.y;
            *(f16x4*)(&s_m[head][lr][c]) = res;
        }
    }

    __syncthreads();

    // ---------- Phase B: aligned_bilinear x2 + sigmoid (8 px/task) ----------
    // One task = 8 output px from one aligned 8B f16x4 read per source row
    // + 1 guarded scalar left-neighbor. sigmoid = rcp(1 + exp2(C*v)) with
    // C = -log2(e) folded into the y-interp (x-interps are linear).
    float* out0 = out + (size_t)inst * (OH * OW) + (size_t)i0 * OW;
    float* out1 = out0 + (size_t)n_inst * (OH * OW);

    const float C = -1.44269504f;     // -log2(e)
    const int NU = OW / 8;            // 50 groups per output row
    const int ntaskb = TH * NU;       // 1250
    for (int t = tid; t < ntaskb; t += BLOCK) {
        const int row = t / NU;
        const int u   = t - row * NU;
        const int i   = i0 + row;
        const int ip  = (i > 0) ? (i - 1) : 0;
        const int y0  = ip >> 1;
        const float wy = (ip & 1) ? 0.5f : 0.0f;
        const int lr0 = y0 - r_begin;
        const int r1c = (y0 + 1 <= Hh - 1) ? (y0 + 1) : (Hh - 1);
        const int lr1 = r1c - r_begin;

        #pragma unroll
        for (int head = 0; head < 2; head++) {
            const f16x4 A0h = *(const f16x4*)(&s_m[head][lr0][4 * u]);
            const f16x4 A1h = *(const f16x4*)(&s_m[head][lr1][4 * u]);
            float p0 = 0.0f, p1 = 0.0f;
            if (u > 0) {
                p0 = (float)s_m[head][lr0][4 * u - 1];
                p1 = (float)s_m[head][lr1][4 * u - 1];
            }
            float Bv[4];
            #pragma unroll
            for (int m = 0; m < 4; m++) {
                const float a0 = (float)A0h[m], a1 = (float)A1h[m];
                Bv[m] = (a0 + (a1 - a0) * wy) * C;
            }
            const float PB = (p0 + (p1 - p0) * wy) * C;

            float e[8];
            e[0] = (u > 0) ? 0.5f * (PB + Bv[0]) : Bv[0];
            e[1] = Bv[0];
            e[2] = 0.5f * (Bv[0] + Bv[1]);
            e[3] = Bv[1];
            e[4] = 0.5f * (Bv[1] + Bv[2]);
            e[5] = Bv[2];
            e[6] = 0.5f * (Bv[2] + Bv[3]);
            e[7] = Bv[3];

            f32x4 lo, hi;
            #pragma unroll
            for (int k = 0; k < 4; k++) {
                lo[k] = __builtin_amdgcn_rcpf(1.0f + __builtin_amdgcn_exp2f(e[k]));
                hi[k] = __builtin_amdgcn_rcpf(1.0f + __builtin_amdgcn_exp2f(e[4 + k]));
            }

            float* dst = (head ? out1 : out0) + row * OW + 8 * u;
            __builtin_nontemporal_store(lo, (f32x4*)dst);
            __builtin_nontemporal_store(hi, (f32x4*)(dst + 4));
        }
    }
}

extern "C" void kernel_launch(void* const* d_in, const int* in_sizes, int n_in,
                              void* d_out, int out_size, void* d_ws, size_t ws_size,
                              hipStream_t stream) {
    const float* mask_feats = (const float*)d_in[0];
    const float* mparams    = (const float*)d_in[1];
    const float* bparams    = (const float*)d_in[2];
    const float* ilocs      = (const float*)d_in[3];
    const int*   im_inds    = (const int*)d_in[4];
    const int*   fpn_levels = (const int*)d_in[5];
    const int*   stride_p   = (const int*)d_in[6];
    float* out = (float*)d_out;

    const int n_inst = in_sizes[1] / NP;      // 128
    dim3 grid(OH / TH, n_inst);               // (16, 128)
    dim3 block(BLOCK);
    hipLaunchKernelGGL(dmh_fused, grid, block, 0, stream,
                       mask_feats, mparams, bparams, ilocs,
                       im_inds, fpn_levels, stride_p, out, n_inst);
}

// Round 14
// 73.930 us; speedup vs baseline: 1.4155x; 1.2677x over previous
//
#include <hip/hip_runtime.h>

// CondInst dynamic mask head, fused (R14).
// mask_feats (2,8,200,200) f32, params (128,169) f32 x2, locs (128,2) f32,
// im_inds/fpn_levels int32, stride scalar int (=8).
// Output: 2 x (128,1,400,400) f32 concat flat.
//
// R14: Phase A is STRAIGHT-LINE — one 4-px chunk per thread, no loop, so no
// anti-hoisting memory clobber is needed (the clobber forced per-iteration
// re-materialization of addresses/constants/weights = the hidden VALU tax
// in R4-R13). BLOCK=512, TH=16 -> npx=2000 = 500 chunks <= 512 threads.
// Everything else = R11: weights packed in LDS, pk-fma, f16 tile, fast
// sigmoid (exp2+rcp, -log2e folded into y-interp), nt f32x4 stores.

#define BLOCK 512
#define Hh 200
#define Ww 200
#define NP 169
#define TH 16      // output rows per tile
#define MAXR 10    // max source rows per tile (factor=2)
#define OW 400
#define OH 400

typedef float f32x4 __attribute__((ext_vector_type(4)));
typedef float f32x2 __attribute__((ext_vector_type(2)));
typedef _Float16 f16x4 __attribute__((ext_vector_type(4)));

__device__ __forceinline__ f32x2 splat2(float v) { f32x2 r; r.x = v; r.y = v; return r; }
__device__ __forceinline__ f32x2 pkfma(f32x2 a, f32x2 b, f32x2 c) {
    return __builtin_elementwise_fma(a, b, c);
}

// packed per-head layout (192 floats, 16B-aligned rows):
//   w0 rows (8 x 10) stride 12 -> [0,96) ; w1 (8 x 8) -> [96,160)
//   w2 (8) -> [160,168) ; b0 [168,176) ; b1 [176,184) ; b2 [184]
__device__ __forceinline__ int park_dst(int k) {
    if (k < 80)  return (k / 10) * 12 + (k % 10);
    if (k < 144) return 96 + (k - 80);
    if (k < 152) return 160 + (k - 144);
    if (k < 160) return 168 + (k - 152);
    if (k < 168) return 176 + (k - 160);
    return 184;
}

// 3-layer MLP on 4 px (xa = px{0,1}, xb = px{2,3}); weights at P (LDS).
__device__ __forceinline__ void mlp4(const float* __restrict__ P,
    const f32x2 (&xa)[10], const f32x2 (&xb)[10], f32x2& oa_, f32x2& ob_)
{
    const f32x2 zero = splat2(0.0f);

    f32x2 h1a[8], h1b[8];
    #pragma unroll
    for (int o = 0; o < 8; o++) {
        const f32x4 wa = *(const f32x4*)(P + o * 12);
        const f32x4 wb = *(const f32x4*)(P + o * 12 + 4);
        const float w8 = P[o * 12 + 8];
        const float w9 = P[o * 12 + 9];
        f32x2 aa = splat2(P[168 + o]);
        f32x2 ab = aa;
        aa = pkfma(splat2(wa.x), xa[0], aa); ab = pkfma(splat2(wa.x), xb[0], ab);
        aa = pkfma(splat2(wa.y), xa[1], aa); ab = pkfma(splat2(wa.y), xb[1], ab);
        aa = pkfma(splat2(wa.z), xa[2], aa); ab = pkfma(splat2(wa.z), xb[2], ab);
        aa = pkfma(splat2(wa.w), xa[3], aa); ab = pkfma(splat2(wa.w), xb[3], ab);
        aa = pkfma(splat2(wb.x), xa[4], aa); ab = pkfma(splat2(wb.x), xb[4], ab);
        aa = pkfma(splat2(wb.y), xa[5], aa); ab = pkfma(splat2(wb.y), xb[5], ab);
        aa = pkfma(splat2(wb.z), xa[6], aa); ab = pkfma(splat2(wb.z), xb[6], ab);
        aa = pkfma(splat2(wb.w), xa[7], aa); ab = pkfma(splat2(wb.w), xb[7], ab);
        aa = pkfma(splat2(w8),   xa[8], aa); ab = pkfma(splat2(w8),   xb[8], ab);
        aa = pkfma(splat2(w9),   xa[9], aa); ab = pkfma(splat2(w9),   xb[9], ab);
        h1a[o] = __builtin_elementwise_max(aa, zero);
        h1b[o] = __builtin_elementwise_max(ab, zero);
    }

    f32x2 h2a[8], h2b[8];
    #pragma unroll
    for (int o = 0; o < 8; o++) {
        const f32x4 wa = *(const f32x4*)(P + 96 + o * 8);
        const f32x4 wb = *(const f32x4*)(P + 96 + o * 8 + 4);
        f32x2 aa = splat2(P[176 + o]);
        f32x2 ab = aa;
        aa = pkfma(splat2(wa.x), h1a[0], aa); ab = pkfma(splat2(wa.x), h1b[0], ab);
        aa = pkfma(splat2(wa.y), h1a[1], aa); ab = pkfma(splat2(wa.y), h1b[1], ab);
        aa = pkfma(splat2(wa.z), h1a[2], aa); ab = pkfma(splat2(wa.z), h1b[2], ab);
        aa = pkfma(splat2(wa.w), h1a[3], aa); ab = pkfma(splat2(wa.w), h1b[3], ab);
        aa = pkfma(splat2(wb.x), h1a[4], aa); ab = pkfma(splat2(wb.x), h1b[4], ab);
        aa = pkfma(splat2(wb.y), h1a[5], aa); ab = pkfma(splat2(wb.y), h1b[5], ab);
        aa = pkfma(splat2(wb.z), h1a[6], aa); ab = pkfma(splat2(wb.z), h1b[6], ab);
        aa = pkfma(splat2(wb.w), h1a[7], aa); ab = pkfma(splat2(wb.w), h1b[7], ab);
        h2a[o] = __builtin_elementwise_max(aa, zero);
        h2b[o] = __builtin_elementwise_max(ab, zero);
    }

    const f32x4 wa = *(const f32x4*)(P + 160);
    const f32x4 wb = *(const f32x4*)(P + 164);
    f32x2 aa = splat2(P[184]);
    f32x2 ab = aa;
    aa = pkfma(splat2(wa.x), h2a[0], aa); ab = pkfma(splat2(wa.x), h2b[0], ab);
    aa = pkfma(splat2(wa.y), h2a[1], aa); ab = pkfma(splat2(wa.y), h2b[1], ab);
    aa = pkfma(splat2(wa.z), h2a[2], aa); ab = pkfma(splat2(wa.z), h2b[2], ab);
    aa = pkfma(splat2(wa.w), h2a[3], aa); ab = pkfma(splat2(wa.w), h2b[3], ab);
    aa = pkfma(splat2(wb.x), h2a[4], aa); ab = pkfma(splat2(wb.x), h2b[4], ab);
    aa = pkfma(splat2(wb.y), h2a[5], aa); ab = pkfma(splat2(wb.y), h2b[5], ab);
    aa = pkfma(splat2(wb.z), h2a[6], aa); ab = pkfma(splat2(wb.z), h2b[6], ab);
    aa = pkfma(splat2(wb.w), h2a[7], aa); ab = pkfma(splat2(wb.w), h2b[7], ab);
    oa_ = aa; ob_ = ab;
}

__global__ __launch_bounds__(BLOCK, 4) void dmh_fused(
    const float* __restrict__ mask_feats,
    const float* __restrict__ mparams,
    const float* __restrict__ bparams,
    const float* __restrict__ ilocs,
    const int*   __restrict__ im_inds,
    const int*   __restrict__ fpn_levels,
    const int*   __restrict__ stride_p,
    float* __restrict__ out,
    int n_inst)
{
    __shared__ __align__(16) float s_par[2 * 192];         // 1.5 KB
    __shared__ __align__(16) _Float16 s_m[2][MAXR][Ww];    // 8 KB

    const int tid  = threadIdx.x;
    const int tile = blockIdx.x;   // 0..24
    const int inst = blockIdx.y;

    if (tid < 2 * NP) {
        const int head = (tid < NP) ? 0 : 1;
        const int k = tid - head * NP;
        const float v = head ? bparams[inst * NP + k] : mparams[inst * NP + k];
        s_par[head * 192 + park_dst(k)] = v;
    }

    const int   s    = stride_p[0];       // 8
    const int   half = s >> 1;
    const int   im   = im_inds[inst];
    const int   lvl  = fpn_levels[inst];
    const float inv_soi = 1.0f / (float)(64 << lvl);  // SOI = 64*2^lvl exactly
    const float ixl = ilocs[inst * 2 + 0];
    const float iyl = ilocs[inst * 2 + 1];

    const int i0 = tile * TH;
    const int r_begin = ((i0 > 0) ? (i0 - 1) : 0) >> 1;
    int r_end = ((i0 + TH - 2) >> 1) + 1;
    if (r_end > Hh - 1) r_end = Hh - 1;
    const int nrows = r_end - r_begin + 1;   // 9 or 10

    __syncthreads();

    // ---------- Phase A: one 4-px chunk per thread, straight-line ----------
    const int npx = nrows * Ww;               // 1800 or 2000
    if (tid * 4 < npx) {
        const int lr = tid / (Ww / 4);        // chunk row
        const int c  = (tid - lr * (Ww / 4)) * 4;
        const int r  = r_begin + lr;
        const float* fbase = mask_feats + (size_t)im * 8 * Hh * Ww;

        f32x2 xa[10], xb[10];
        {
            const float ry   = (iyl - (float)(r * s + half)) * inv_soi;
            const float step = -(float)s * inv_soi;
            const float cx0  = (ixl - (float)(c * s + half)) * inv_soi;
            xa[0].x = cx0;            xa[0].y = cx0 + step;
            xb[0].x = cx0 + 2*step;   xb[0].y = cx0 + 3*step;
            xa[1] = splat2(ry);       xb[1] = xa[1];
            const float* fp = fbase + r * Ww + c;
            #pragma unroll
            for (int ch = 0; ch < 8; ch++) {
                const f32x4 f = *(const f32x4*)(fp + ch * (Hh * Ww));
                xa[2 + ch].x = f.x; xa[2 + ch].y = f.y;
                xb[2 + ch].x = f.z; xb[2 + ch].y = f.w;
            }
        }

        #pragma unroll 1
        for (int head = 0; head < 2; head++) {
            f32x2 oa, ob;
            mlp4(s_par + head * 192, xa, xb, oa, ob);
            f16x4 res;
            res.x = (_Float16)oa.x; res.y = (_Float16)oa.y;
            res.z = (_Float16)ob.x; res.w = (_Float16)ob.y;
            *(f16x4*)(&s_m[head][lr][c]) = res;
        }
    }

    __syncthreads();

    // ---------- Phase B: aligned_bilinear x2 + sigmoid (8 px/task) ----------
    float* out0 = out + (size_t)inst * (OH * OW) + (size_t)i0 * OW;
    float* out1 = out0 + (size_t)n_inst * (OH * OW);

    const float C = -1.44269504f;     // -log2(e)
    const int NU = OW / 8;            // 50 groups per output row
    const int ntaskb = TH * NU;       // 800
    for (int t = tid; t < ntaskb; t += BLOCK) {
        const int row = t / NU;
        const int u   = t - row * NU;
        const int i   = i0 + row;
        const int ip  = (i > 0) ? (i - 1) : 0;
        const int y0  = ip >> 1;
        const float wy = (ip & 1) ? 0.5f : 0.0f;
        const int lr0 = y0 - r_begin;
        const int r1c = (y0 + 1 <= Hh - 1) ? (y0 + 1) : (Hh - 1);
        const int lr1 = r1c - r_begin;

        #pragma unroll
        for (int head = 0; head < 2; head++) {
            const f16x4 A0h = *(const f16x4*)(&s_m[head][lr0][4 * u]);
            const f16x4 A1h = *(const f16x4*)(&s_m[head][lr1][4 * u]);
            float p0 = 0.0f, p1 = 0.0f;
            if (u > 0) {
                p0 = (float)s_m[head][lr0][4 * u - 1];
                p1 = (float)s_m[head][lr1][4 * u - 1];
            }
            float Bv[4];
            #pragma unroll
            for (int m = 0; m < 4; m++) {
                const float a0 = (float)A0h[m], a1 = (float)A1h[m];
                Bv[m] = (a0 + (a1 - a0) * wy) * C;
            }
            const float PB = (p0 + (p1 - p0) * wy) * C;

            float e[8];
            e[0] = (u > 0) ? 0.5f * (PB + Bv[0]) : Bv[0];
            e[1] = Bv[0];
            e[2] = 0.5f * (Bv[0] + Bv[1]);
            e[3] = Bv[1];
            e[4] = 0.5f * (Bv[1] + Bv[2]);
            e[5] = Bv[2];
            e[6] = 0.5f * (Bv[2] + Bv[3]);
            e[7] = Bv[3];

            f32x4 lo, hi;
            #pragma unroll
            for (int k = 0; k < 4; k++) {
                lo[k] = __builtin_amdgcn_rcpf(1.0f + __builtin_amdgcn_exp2f(e[k]));
                hi[k] = __builtin_amdgcn_rcpf(1.0f + __builtin_amdgcn_exp2f(e[4 + k]));
            }

            float* dst = (head ? out1 : out0) + row * OW + 8 * u;
            __builtin_nontemporal_store(lo, (f32x4*)dst);
            __builtin_nontemporal_store(hi, (f32x4*)(dst + 4));
        }
    }
}

extern "C" void kernel_launch(void* const* d_in, const int* in_sizes, int n_in,
                              void* d_out, int out_size, void* d_ws, size_t ws_size,
                              hipStream_t stream) {
    const float* mask_feats = (const float*)d_in[0];
    const float* mparams    = (const float*)d_in[1];
    const float* bparams    = (const float*)d_in[2];
    const float* ilocs      = (const float*)d_in[3];
    const int*   im_inds    = (const int*)d_in[4];
    const int*   fpn_levels = (const int*)d_in[5];
    const int*   stride_p   = (const int*)d_in[6];
    float* out = (float*)d_out;

    const int n_inst = in_sizes[1] / NP;      // 128
    dim3 grid(OH / TH, n_inst);               // (25, 128)
    dim3 block(BLOCK);
    hipLaunchKernelGGL(dmh_fused, grid, block, 0, stream,
                       mask_feats, mparams, bparams, ilocs,
                       im_inds, fpn_levels, stride_p, out, n_inst);
}

// Round 15
// 66.047 us; speedup vs baseline: 1.5845x; 1.1194x over previous
//
#include <hip/hip_runtime.h>

// CondInst dynamic mask head, fused (R15 = R11 + b128-only weight layout).
// mask_feats (2,8,200,200) f32, params (128,169) f32 x2, locs (128,2) f32,
// im_inds/fpn_levels int32, stride scalar int (=8).
// Output: 2 x (128,1,400,400) f32 concat flat.
//
// R15 change (isolated): LDS weight layout packed so ALL Phase-A weight
// reads are b128 (L1 rows 12f [10w,bias,pad] = 3 reads; L2 biases preloaded
// 2xb128/head, rows 2xb128; L3 3 reads): 134 -> 90 LDS instrs per 4-px chunk.

#define BLOCK 256
#define Hh 200
#define Ww 200
#define NP 169
#define TH 25      // output rows per tile
#define MAXR 14    // max head rows needed per tile (factor=2)
#define OW 400
#define OH 400
#define PSTR 192   // per-head packed-param stride (floats)

typedef float f32x4 __attribute__((ext_vector_type(4)));
typedef float f32x2 __attribute__((ext_vector_type(2)));
typedef _Float16 f16x4 __attribute__((ext_vector_type(4)));

__device__ __forceinline__ f32x2 splat2(float v) { f32x2 r; r.x = v; r.y = v; return r; }
__device__ __forceinline__ f32x2 pkfma(f32x2 a, f32x2 b, f32x2 c) {
    return __builtin_elementwise_fma(a, b, c);
}

// packed per-head layout (PSTR floats, all reads 16B-aligned b128):
//   L1 row o at o*12: [w0..w9, bias, pad]            (o = 0..7) -> [0,96)
//   L2 w rows (8 x 8) -> [96,160) ; L2 biases -> [160,168)
//   L3 w -> [168,176) ; L3 bias -> [176]
__device__ __forceinline__ int park_dst(int k) {
    if (k < 80)  return (k / 10) * 12 + (k % 10);   // L1 w
    if (k < 144) return 96 + (k - 80);              // L2 w
    if (k < 152) return 168 + (k - 144);            // L3 w
    if (k < 160) return (k - 152) * 12 + 10;        // L1 b
    if (k < 168) return 160 + (k - 160);            // L2 b
    return 176;                                      // L3 b
}

// 3-layer MLP on 4 px (xa = px{0,1}, xb = px{2,3}); weights at P (LDS).
__device__ __forceinline__ void mlp4(const float* __restrict__ P,
    const f32x2 (&xa)[10], const f32x2 (&xb)[10], f32x2& oa_, f32x2& ob_)
{
    const f32x2 zero = splat2(0.0f);

    f32x2 h1a[8], h1b[8];
    #pragma unroll
    for (int o = 0; o < 8; o++) {
        const f32x4 wa = *(const f32x4*)(P + o * 12);       // w0..w3
        const f32x4 wb = *(const f32x4*)(P + o * 12 + 4);   // w4..w7
        const f32x4 wc = *(const f32x4*)(P + o * 12 + 8);   // w8, w9, bias, pad
        f32x2 aa = splat2(wc.z);
        f32x2 ab = aa;
        aa = pkfma(splat2(wa.x), xa[0], aa); ab = pkfma(splat2(wa.x), xb[0], ab);
        aa = pkfma(splat2(wa.y), xa[1], aa); ab = pkfma(splat2(wa.y), xb[1], ab);
        aa = pkfma(splat2(wa.z), xa[2], aa); ab = pkfma(splat2(wa.z), xb[2], ab);
        aa = pkfma(splat2(wa.w), xa[3], aa); ab = pkfma(splat2(wa.w), xb[3], ab);
        aa = pkfma(splat2(wb.x), xa[4], aa); ab = pkfma(splat2(wb.x), xb[4], ab);
        aa = pkfma(splat2(wb.y), xa[5], aa); ab = pkfma(splat2(wb.y), xb[5], ab);
        aa = pkfma(splat2(wb.z), xa[6], aa); ab = pkfma(splat2(wb.z), xb[6], ab);
        aa = pkfma(splat2(wb.w), xa[7], aa); ab = pkfma(splat2(wb.w), xb[7], ab);
        aa = pkfma(splat2(wc.x), xa[8], aa); ab = pkfma(splat2(wc.x), xb[8], ab);
        aa = pkfma(splat2(wc.y), xa[9], aa); ab = pkfma(splat2(wc.y), xb[9], ab);
        h1a[o] = __builtin_elementwise_max(aa, zero);
        h1b[o] = __builtin_elementwise_max(ab, zero);
    }

    // L2 biases: 2 b128 reads per head pass
    const f32x4 blo = *(const f32x4*)(P + 160);
    const f32x4 bhi = *(const f32x4*)(P + 164);
    const float b1v[8] = {blo.x, blo.y, blo.z, blo.w, bhi.x, bhi.y, bhi.z, bhi.w};

    f32x2 h2a[8], h2b[8];
    #pragma unroll
    for (int o = 0; o < 8; o++) {
        const f32x4 wa = *(const f32x4*)(P + 96 + o * 8);
        const f32x4 wb = *(const f32x4*)(P + 96 + o * 8 + 4);
        f32x2 aa = splat2(b1v[o]);
        f32x2 ab = aa;
        aa = pkfma(splat2(wa.x), h1a[0], aa); ab = pkfma(splat2(wa.x), h1b[0], ab);
        aa = pkfma(splat2(wa.y), h1a[1], aa); ab = pkfma(splat2(wa.y), h1b[1], ab);
        aa = pkfma(splat2(wa.z), h1a[2], aa); ab = pkfma(splat2(wa.z), h1b[2], ab);
        aa = pkfma(splat2(wa.w), h1a[3], aa); ab = pkfma(splat2(wa.w), h1b[3], ab);
        aa = pkfma(splat2(wb.x), h1a[4], aa); ab = pkfma(splat2(wb.x), h1b[4], ab);
        aa = pkfma(splat2(wb.y), h1a[5], aa); ab = pkfma(splat2(wb.y), h1b[5], ab);
        aa = pkfma(splat2(wb.z), h1a[6], aa); ab = pkfma(splat2(wb.z), h1b[6], ab);
        aa = pkfma(splat2(wb.w), h1a[7], aa); ab = pkfma(splat2(wb.w), h1b[7], ab);
        h2a[o] = __builtin_elementwise_max(aa, zero);
        h2b[o] = __builtin_elementwise_max(ab, zero);
    }

    const f32x4 wa = *(const f32x4*)(P + 168);
    const f32x4 wb = *(const f32x4*)(P + 172);
    const float b2 = P[176];
    f32x2 aa = splat2(b2);
    f32x2 ab = aa;
    aa = pkfma(splat2(wa.x), h2a[0], aa); ab = pkfma(splat2(wa.x), h2b[0], ab);
    aa = pkfma(splat2(wa.y), h2a[1], aa); ab = pkfma(splat2(wa.y), h2b[1], ab);
    aa = pkfma(splat2(wa.z), h2a[2], aa); ab = pkfma(splat2(wa.z), h2b[2], ab);
    aa = pkfma(splat2(wa.w), h2a[3], aa); ab = pkfma(splat2(wa.w), h2b[3], ab);
    aa = pkfma(splat2(wb.x), h2a[4], aa); ab = pkfma(splat2(wb.x), h2b[4], ab);
    aa = pkfma(splat2(wb.y), h2a[5], aa); ab = pkfma(splat2(wb.y), h2b[5], ab);
    aa = pkfma(splat2(wb.z), h2a[6], aa); ab = pkfma(splat2(wb.z), h2b[6], ab);
    aa = pkfma(splat2(wb.w), h2a[7], aa); ab = pkfma(splat2(wb.w), h2b[7], ab);
    oa_ = aa; ob_ = ab;
}

__global__ __launch_bounds__(BLOCK, 4) void dmh_fused(
    const float* __restrict__ mask_feats,
    const float* __restrict__ mparams,
    const float* __restrict__ bparams,
    const float* __restrict__ ilocs,
    const int*   __restrict__ im_inds,
    const int*   __restrict__ fpn_levels,
    const int*   __restrict__ stride_p,
    float* __restrict__ out,
    int n_inst)
{
    __shared__ __align__(16) float s_par[2 * PSTR];        // 1.5 KB
    __shared__ __align__(16) _Float16 s_m[2][MAXR][Ww];    // 11.2 KB

    const int tid  = threadIdx.x;
    const int tile = blockIdx.x;   // 0..15
    const int inst = blockIdx.y;

    for (int j = tid; j < 2 * NP; j += BLOCK) {
        const int head = (j < NP) ? 0 : 1;
        const int k = j - head * NP;
        const float v = head ? bparams[inst * NP + k] : mparams[inst * NP + k];
        s_par[head * PSTR + park_dst(k)] = v;
    }

    const int   s    = stride_p[0];       // 8
    const int   half = s >> 1;
    const int   im   = im_inds[inst];
    const int   lvl  = fpn_levels[inst];
    const float inv_soi = 1.0f / (float)(64 << lvl);  // SOI = 64*2^lvl exactly
    const float ixl = ilocs[inst * 2 + 0];
    const float iyl = ilocs[inst * 2 + 1];

    const int i0 = tile * TH;
    const int r_begin = ((i0 > 0) ? (i0 - 1) : 0) >> 1;
    int r_end = ((i0 + TH - 2) >> 1) + 1;
    if (r_end > Hh - 1) r_end = Hh - 1;
    const int nrows = r_end - r_begin + 1;   // 13 or 14

    __syncthreads();

    // ---------- Phase A: head MLP at 200-res into LDS (pk-f32, 4 px/chunk) ----------
    const int npx = nrows * Ww;                 // multiple of 4
    const float* fbase = mask_feats + (size_t)im * 8 * Hh * Ww;

    for (int g = tid * 4; g < npx; g += BLOCK * 4) {
        // prevent hoisting of LDS weight loads across iterations (VGPR blowup)
        asm volatile("" ::: "memory");

        const int lr = g / Ww;
        const int c  = g - lr * Ww;             // multiple of 4
        const int r  = r_begin + lr;

        // xa = px {0,1}, xb = px {2,3} for the 10 input channels
        f32x2 xa[10], xb[10];
        {
            const float ry   = (iyl - (float)(r * s + half)) * inv_soi;
            const float step = -(float)s * inv_soi;
            const float cx0  = (ixl - (float)(c * s + half)) * inv_soi;
            xa[0].x = cx0;            xa[0].y = cx0 + step;
            xb[0].x = cx0 + 2*step;   xb[0].y = cx0 + 3*step;
            xa[1] = splat2(ry);       xb[1] = xa[1];
            const float* fp = fbase + r * Ww + c;
            #pragma unroll
            for (int ch = 0; ch < 8; ch++) {
                const f32x4 f = *(const f32x4*)(fp + ch * (Hh * Ww));
                xa[2 + ch].x = f.x; xa[2 + ch].y = f.y;
                xb[2 + ch].x = f.z; xb[2 + ch].y = f.w;
            }
        }

        #pragma unroll 1
        for (int head = 0; head < 2; head++) {
            f32x2 oa, ob;
            mlp4(s_par + head * PSTR, xa, xb, oa, ob);
            f16x4 res;
            res.x = (_Float16)oa.x; res.y = (_Float16)oa.y;
            res.z = (_Float16)ob.x; res.w = (_Float16)ob.y;
            *(f16x4*)(&s_m[head][lr][c]) = res;
        }
    }

    __syncthreads();

    // ---------- Phase B: aligned_bilinear x2 + sigmoid (8 px/task) ----------
    // One task = 8 output px from one aligned 8B f16x4 read per source row
    // + 1 guarded scalar left-neighbor. sigmoid = rcp(1 + exp2(C*v)) with
    // C = -log2(e) folded into the y-interp (x-interps are linear).
    float* out0 = out + (size_t)inst * (OH * OW) + (size_t)i0 * OW;
    float* out1 = out0 + (size_t)n_inst * (OH * OW);

    const float C = -1.44269504f;     // -log2(e)
    const int NU = OW / 8;            // 50 groups per output row
    const int ntaskb = TH * NU;       // 1250
    for (int t = tid; t < ntaskb; t += BLOCK) {
        const int row = t / NU;
        const int u   = t - row * NU;
        const int i   = i0 + row;
        const int ip  = (i > 0) ? (i - 1) : 0;
        const int y0  = ip >> 1;
        const float wy = (ip & 1) ? 0.5f : 0.0f;
        const int lr0 = y0 - r_begin;
        const int r1c = (y0 + 1 <= Hh - 1) ? (y0 + 1) : (Hh - 1);
        const int lr1 = r1c - r_begin;

        #pragma unroll
        for (int head = 0; head < 2; head++) {
            const f16x4 A0h = *(const f16x4*)(&s_m[head][lr0][4 * u]);
            const f16x4 A1h = *(const f16x4*)(&s_m[head][lr1][4 * u]);
            float p0 = 0.0f, p1 = 0.0f;
            if (u > 0) {
                p0 = (float)s_m[head][lr0][4 * u - 1];
                p1 = (float)s_m[head][lr1][4 * u - 1];
            }
            float Bv[4];
            #pragma unroll
            for (int m = 0; m < 4; m++) {
                const float a0 = (float)A0h[m], a1 = (float)A1h[m];
                Bv[m] = (a0 + (a1 - a0) * wy) * C;
            }
            const float PB = (p0 + (p1 - p0) * wy) * C;

            float e[8];
            e[0] = (u > 0) ? 0.5f * (PB + Bv[0]) : Bv[0];
            e[1] = Bv[0];
            e[2] = 0.5f * (Bv[0] + Bv[1]);
            e[3] = Bv[1];
            e[4] = 0.5f * (Bv[1] + Bv[2]);
            e[5] = Bv[2];
            e[6] = 0.5f * (Bv[2] + Bv[3]);
            e[7] = Bv[3];

            f32x4 lo, hi;
            #pragma unroll
            for (int k = 0; k < 4; k++) {
                lo[k] = __builtin_amdgcn_rcpf(1.0f + __builtin_amdgcn_exp2f(e[k]));
                hi[k] = __builtin_amdgcn_rcpf(1.0f + __builtin_amdgcn_exp2f(e[4 + k]));
            }

            float* dst = (head ? out1 : out0) + row * OW + 8 * u;
            __builtin_nontemporal_store(lo, (f32x4*)dst);
            __builtin_nontemporal_store(hi, (f32x4*)(dst + 4));
        }
    }
}

extern "C" void kernel_launch(void* const* d_in, const int* in_sizes, int n_in,
                              void* d_out, int out_size, void* d_ws, size_t ws_size,
                              hipStream_t stream) {
    const float* mask_feats = (const float*)d_in[0];
    const float* mparams    = (const float*)d_in[1];
    const float* bparams    = (const float*)d_in[2];
    const float* ilocs      = (const float*)d_in[3];
    const int*   im_inds    = (const int*)d_in[4];
    const int*   fpn_levels = (const int*)d_in[5];
    const int*   stride_p   = (const int*)d_in[6];
    float* out = (float*)d_out;

    const int n_inst = in_sizes[1] / NP;      // 128
    dim3 grid(OH / TH, n_inst);               // (16, 128)
    dim3 block(BLOCK);
    hipLaunchKernelGGL(dmh_fused, grid, block, 0, stream,
                       mask_feats, mparams, bparams, ilocs,
                       im_inds, fpn_levels, stride_p, out, n_inst);
}